// Round 1
// baseline (376.110 us; speedup 1.0000x reference)
//
#include <hip/hip_runtime.h>
#include <cstddef>

#define BB    16
#define NN    2048
#define BN    (BB * NN)
#define EPSF  1e-9f
#define TPB   512
#define CPT   4                 // columns (rows) per thread -> covers all 2048
#define SPLIT 32                // reduction-dim split
#define TILE  64                // NN/SPLIT rows (or cols) staged per block
#define UFLO  -151.0f           // exp2(arg) == +0.0f for arg < this (incl. denormal rounding)

// OCML native exp2 is always linkable; builtin preferred (both -> v_exp_f32).
extern "C" __device__ float __ocml_native_exp2_f32(float);
__device__ __forceinline__ float fast_exp2(float x) {
#if __has_builtin(__builtin_amdgcn_exp2f)
    return __builtin_amdgcn_exp2f(x);
#else
    return __ocml_native_exp2_f32(x);
#endif
}

__device__ __forceinline__ float f4c(float4 v, int u) {   // u is compile-time (unrolled)
    return (u == 0) ? v.x : ((u == 1) ? v.y : ((u == 2) ? v.z : v.w));
}

__device__ __forceinline__ float block_sum(float v, int t, float* tmp8) {
#pragma unroll
    for (int o = 32; o > 0; o >>= 1) v += __shfl_down(v, o, 64);
    __syncthreads();                       // protect tmp8 reuse across calls
    if ((t & 63) == 0) tmp8[t >> 6] = v;
    __syncthreads();
    float s = 0.0f;
#pragma unroll
    for (int w = 0; w < TPB / 64; w++) s += tmp8[w];
    return s;
}

// passA (fused with prev round's combB):
//   prologue: cur_k = max(cur_{k-1}*(1-RS_{k-1}),0); out += sum cur_{k-1}*RR_{k-1};
//             zero RS/RR[k&1] for this round's passB; write cur_k.
//   main:     S[m] += sum_n e, T[m] += sum_n e*cur_k[n]   (atomic partials)
// SKIP=1 (rounds k<=2, |c1| >= 1476): wave-uniform underflow skip — exp2(arg)
// is exactly +0.0f for arg < UFLO, so skipping exp+accum when no lane is above
// threshold is bit-identical.
template<int SKIP>
__global__ __launch_bounds__(TPB, 4) void passA(
    const float* __restrict__ preds, const float* __restrict__ labels,
    const float* __restrict__ curprev, float* __restrict__ curout,
    const float* __restrict__ RSprev, const float* __restrict__ RRprev,
    float* __restrict__ RSz, float* __restrict__ RRz,
    float* __restrict__ Sacc, float* __restrict__ Tacc,
    float* __restrict__ out, float c1, int k)
{
    __shared__ float4 s_p[TILE];          // (px,py,pz, c1*|p|^2)
    __shared__ float4 s_cu4[TILE / 4];    // cur packed 4-wide (one b128 per 4 j)
    __shared__ float  s_red;
    int blk = blockIdx.x;
    int split = blk & (SPLIT - 1), b = blk >> 5;
    int t = threadIdx.x;
    int base = b * NN;

    if (t < TILE) {
        int idx = base + split * TILE + t;
        const float* p = preds + (size_t)idx * 3;
        float px = p[0], py = p[1], pz = p[2];
        float pn = px * px + py * py + pz * pz;
        float cu, contrib = 0.0f;
        if (k == 0) cu = 1.0f;
        else {
            float cup = curprev[idx], rs = RSprev[idx], rr = RRprev[idx];
            contrib = cup * rr;                       // round k-1 result term
            cu = fmaxf(cup * (1.0f - rs), 0.0f);
        }
        s_p[t] = make_float4(px, py, pz, c1 * pn);
        ((float*)s_cu4)[t] = cu;
        curout[idx] = cu;
        RSz[idx] = 0.0f; RRz[idx] = 0.0f;             // for this round's passB
        if (k > 0) {                                  // t<64 == exactly wave 0
#pragma unroll
            for (int o = 32; o > 0; o >>= 1) contrib += __shfl_down(contrib, o, 64);
            if (t == 0) s_red = contrib;
        }
    }

    // thread-held columns (labels), prescaled by c1
    float gx[CPT], gy[CPT], gz[CPT], am[CPT], Sa[CPT], Ta[CPT];
    float n2c1 = -2.0f * c1;
#pragma unroll
    for (int c = 0; c < CPT; c++) {
        const float* l = labels + (size_t)(base + t + c * TPB) * 3;
        float lx = l[0], ly = l[1], lz = l[2];
        gx[c] = n2c1 * lx; gy[c] = n2c1 * ly; gz[c] = n2c1 * lz;
        am[c] = c1 * (lx * lx + ly * ly + lz * lz);
        Sa[c] = 0.0f; Ta[c] = 0.0f;
    }
    __syncthreads();
    if (k > 0 && t == 0) atomicAdd(out, s_red);

#pragma unroll 2
    for (int j4 = 0; j4 < TILE / 4; j4++) {
        float4 cu4 = s_cu4[j4];
#pragma unroll
        for (int u = 0; u < 4; u++) {
            float4 P = s_p[j4 * 4 + u];
            float cu = f4c(cu4, u);
#pragma unroll
            for (int c = 0; c < CPT; c++) {
                float arg = fmaf(P.x, gx[c], fmaf(P.y, gy[c], fmaf(P.z, gz[c], P.w + am[c])));
                if constexpr (SKIP) {
                    if (__any(arg > UFLO)) {
                        float e = fast_exp2(arg);
                        Sa[c] += e;
                        Ta[c] = fmaf(e, cu, Ta[c]);
                    }
                } else {
                    float e = fast_exp2(arg);
                    Sa[c] += e;
                    Ta[c] = fmaf(e, cu, Ta[c]);
                }
            }
        }
    }
#pragma unroll
    for (int c = 0; c < CPT; c++) {
        int idx = base + t + c * TPB;
        atomicAdd(&Sacc[idx], Sa[c]);
        atomicAdd(&Tacc[idx], Ta[c]);
    }
}

// passB (fused with combA):
//   prologue: per staged column m: cc = cost*bw/D1 (from S,T,cost); write cost_{k+1},
//             zero S/T[(k+1)&1] for next round's passA.
//   main:     RS[n] += sum_m e*cc; RR[n] += sum_m e*cc*pw (via (sum w*arg)/c1).
template<int SKIP>
__global__ __launch_bounds__(TPB, 4) void passB(
    const float* __restrict__ preds, const float* __restrict__ labels,
    const float* __restrict__ Sread, const float* __restrict__ Tread,
    const float* __restrict__ costprev, float* __restrict__ costout,
    float* __restrict__ Sz, float* __restrict__ Tz,
    float* __restrict__ RSacc, float* __restrict__ RRacc,
    float c1, float invc1, int k)
{
    __shared__ float4 s_l[TILE];
    __shared__ float4 s_cc4[TILE / 4];
    int blk = blockIdx.x;
    int split = blk & (SPLIT - 1), b = blk >> 5;
    int t = threadIdx.x;
    int base = b * NN;

    if (t < TILE) {
        int idx = base + split * TILE + t;
        const float* l = labels + (size_t)idx * 3;
        float lx = l[0], ly = l[1], lz = l[2];
        float lm2 = lx * lx + ly * ly + lz * lz;
        float S = Sread[idx], T = Tread[idx];
        float cost = (k == 0) ? 1.0f : costprev[idx];
        float D1 = fmaf(cost, S, EPSF);
        float S2 = cost * T / D1;
        float bw = fminf(cost / (S2 + EPSF), 1.0f);
        float cc = cost * bw / D1;
        costout[idx] = fmaxf(fmaf(-S2, bw, cost), 0.0f);
        Sz[idx] = 0.0f; Tz[idx] = 0.0f;               // for next round's passA
        s_l[t] = make_float4(-2.0f * c1 * lx, -2.0f * c1 * ly,
                             -2.0f * c1 * lz, c1 * lm2);
        ((float*)s_cc4)[t] = cc;
    }

    float px[CPT], py[CPT], pz[CPT], qq[CPT], RSa[CPT], RRa[CPT];
#pragma unroll
    for (int c = 0; c < CPT; c++) {
        const float* p = preds + (size_t)(base + t + c * TPB) * 3;
        px[c] = p[0]; py[c] = p[1]; pz[c] = p[2];
        qq[c] = c1 * (px[c] * px[c] + py[c] * py[c] + pz[c] * pz[c]);
        RSa[c] = 0.0f; RRa[c] = 0.0f;
    }
    __syncthreads();

#pragma unroll 2
    for (int j4 = 0; j4 < TILE / 4; j4++) {
        float4 cc4 = s_cc4[j4];
#pragma unroll
        for (int u = 0; u < 4; u++) {
            float4 L = s_l[j4 * 4 + u];
            float ccj = f4c(cc4, u);
#pragma unroll
            for (int c = 0; c < CPT; c++) {
                float arg = fmaf(px[c], L.x, fmaf(py[c], L.y, fmaf(pz[c], L.z, qq[c] + L.w)));
                if constexpr (SKIP) {
                    if (__any(arg > UFLO)) {
                        float e = fast_exp2(arg);
                        float w = e * ccj;
                        RSa[c] += w;
                        RRa[c] = fmaf(w, arg, RRa[c]);
                    }
                } else {
                    float e = fast_exp2(arg);
                    float w = e * ccj;
                    RSa[c] += w;
                    RRa[c] = fmaf(w, arg, RRa[c]);     // sum w*arg; *1/c1 at end
                }
            }
        }
    }
#pragma unroll
    for (int c = 0; c < CPT; c++) {
        int idx = base + t + c * TPB;
        atomicAdd(&RSacc[idx], RSa[c]);
        atomicAdd(&RRacc[idx], RRa[c] * invc1);
    }
}

// Round 9 (ef=0 -> e==1 exactly) collapses algebraically:
//   passA(9): S[m]=2048 (exact const), T[m]=sum_n cur9[n] (batch scalar Cb)
//   passB(9): RR9[n] = sum_m cc*pw = A*|p_n|^2 + B - 2 p_n.V,
//             A=sum cc, B=sum cc*|l|^2, V=sum cc*l   (O(N) reductions)
//   out += sum cur8*RR8 (round-8 term) + sum cur9*RR9 (round-9 term, ex-finalK)
__global__ __launch_bounds__(TPB, 1) void k9(
    const float* __restrict__ preds, const float* __restrict__ labels,
    const float* __restrict__ cur8, const float* __restrict__ RS8,
    const float* __restrict__ RR8, const float* __restrict__ cost9,
    float* __restrict__ out)
{
    __shared__ float tmp8[TPB / 64];
    int b = blockIdx.x, t = threadIdx.x;
    int base = b * NN;

    float cu9[CPT];
    float contrib = 0.0f, csum = 0.0f;
#pragma unroll
    for (int c = 0; c < CPT; c++) {
        int idx = base + t + c * TPB;
        float cup = cur8[idx];
        contrib = fmaf(cup, RR8[idx], contrib);       // round-8 result term
        float cu = fmaxf(cup * (1.0f - RS8[idx]), 0.0f);
        cu9[c] = cu; csum += cu;
    }
    float contribT = block_sum(contrib, t, tmp8);
    float Cb = block_sum(csum, t, tmp8);              // T[m] == Cb for all m

    float A = 0.0f, Bs = 0.0f, Vx = 0.0f, Vy = 0.0f, Vz = 0.0f;
#pragma unroll
    for (int c = 0; c < CPT; c++) {
        int idx = base + t + c * TPB;
        const float* l = labels + (size_t)idx * 3;
        float lx = l[0], ly = l[1], lz = l[2];
        float cost = cost9[idx];
        float D1 = fmaf(cost, 2048.0f, EPSF);         // S == 2048 exactly
        float S2 = cost * Cb / D1;
        float bw = fminf(cost / (S2 + EPSF), 1.0f);
        float cc = cost * bw / D1;
        A += cc;
        Bs = fmaf(cc, lx * lx + ly * ly + lz * lz, Bs);
        Vx = fmaf(cc, lx, Vx); Vy = fmaf(cc, ly, Vy); Vz = fmaf(cc, lz, Vz);
    }
    float At  = block_sum(A, t, tmp8);
    float Bt  = block_sum(Bs, t, tmp8);
    float Vxt = block_sum(Vx, t, tmp8);
    float Vyt = block_sum(Vy, t, tmp8);
    float Vzt = block_sum(Vz, t, tmp8);

    float acc = 0.0f;
#pragma unroll
    for (int c = 0; c < CPT; c++) {
        int idx = base + t + c * TPB;
        const float* p = preds + (size_t)idx * 3;
        float x = p[0], y = p[1], z = p[2];
        float pn = x * x + y * y + z * z;
        float rr = fmaf(At, pn, Bt) - 2.0f * (x * Vxt + y * Vyt + z * Vzt);
        acc = fmaf(cu9[c], rr, acc);                  // round-9 result term
    }
    float accT = block_sum(acc, t, tmp8);
    if (t == 0) atomicAdd(out, contribT + accT);
}

extern "C" void kernel_launch(void* const* d_in, const int* in_sizes, int n_in,
                              void* d_out, int out_size, void* d_ws, size_t ws_size,
                              hipStream_t stream) {
    const float* preds  = (const float*)d_in[0];
    const float* labels = (const float*)d_in[1];
    float* out = (float*)d_out;
    float* ws  = (float*)d_ws;

    // layout: S0 T0 S1 T1 RS0 RR0 RS1 RR1 cur0 cur1 cost0 cost1  (12*BN floats = 1.5 MB)
    float* S[2]     = {ws + 0 * BN, ws + 2 * BN};
    float* T[2]     = {ws + 1 * BN, ws + 3 * BN};
    float* RS[2]    = {ws + 4 * BN, ws + 6 * BN};
    float* RR[2]    = {ws + 5 * BN, ws + 7 * BN};
    float* curb[2]  = {ws + 8 * BN, ws + 9 * BN};
    float* costb[2] = {ws + 10 * BN, ws + 11 * BN};

    hipMemsetAsync(d_out, 0, sizeof(float), stream);
    hipMemsetAsync(ws, 0, (size_t)2 * BN * sizeof(float), stream);  // S[0], T[0]

    static const float efs[9] = {-16384.0f, -4096.0f, -1024.0f, -256.0f, -64.0f,
                                 -16.0f, -4.0f, -1.0f, -0.25f};
    const float log2e = 1.44269504088896f;
    for (int k = 0; k < 9; k++) {
        float c1 = efs[k] * log2e;
        float invc1 = 1.0f / c1;
        int pk = k & 1, pp = (k + 1) & 1;   // pp == (k-1)&1 for k>=1
        if (k <= 2) {
            passA<1><<<512, TPB, 0, stream>>>(preds, labels,
                curb[pp], curb[pk], RS[pp], RR[pp], RS[pk], RR[pk],
                S[pk], T[pk], out, c1, k);
            passB<1><<<512, TPB, 0, stream>>>(preds, labels,
                S[pk], T[pk], costb[pk], costb[pp], S[pp], T[pp],
                RS[pk], RR[pk], c1, invc1, k);
        } else {
            passA<0><<<512, TPB, 0, stream>>>(preds, labels,
                curb[pp], curb[pk], RS[pp], RR[pp], RS[pk], RR[pk],
                S[pk], T[pk], out, c1, k);
            passB<0><<<512, TPB, 0, stream>>>(preds, labels,
                S[pk], T[pk], costb[pk], costb[pp], S[pp], T[pp],
                RS[pk], RR[pk], c1, invc1, k);
        }
    }
    // after k=8: cur8=curb[0], RS8=RS[0], RR8=RR[0], cost9=costb[1]
    k9<<<BB, TPB, 0, stream>>>(preds, labels, curb[0], RS[0], RR[0], costb[1], out);
}

// Round 2
// 309.710 us; speedup vs baseline: 1.2144x; 1.2144x over previous
//
#include <hip/hip_runtime.h>
#include <cstddef>

#define BB    16
#define NN    2048
#define BN    (BB * NN)
#define EPSF  1e-9f
#define TPB   512
#define CPT   2                 // columns (rows) per thread
#define SPLIT 16                // reduction-dim split
#define TILE  128               // NN/SPLIT rows (or cols) staged per block
#define CHUNK 1024              // TPB*CPT columns (rows) per block
#define K9C   4                 // k9 kernel: 512 threads x 4 = 2048

typedef float v2f __attribute__((ext_vector_type(2)));
typedef float v4f __attribute__((ext_vector_type(4)));

// OCML native exp2 is always linkable; builtin preferred (both -> v_exp_f32).
extern "C" __device__ float __ocml_native_exp2_f32(float);
__device__ __forceinline__ float fast_exp2(float x) {
#if __has_builtin(__builtin_amdgcn_exp2f)
    return __builtin_amdgcn_exp2f(x);
#else
    return __ocml_native_exp2_f32(x);
#endif
}

// Packed fp32 (VOP3P): 2 IEEE fp32 ops per VALU issue slot.
__device__ __forceinline__ v2f pk_fma(v2f a, v2f b, v2f c) {
    v2f d;
    asm("v_pk_fma_f32 %0, %1, %2, %3" : "=v"(d) : "v"(a), "v"(b), "v"(c));
    return d;
}
__device__ __forceinline__ v2f pk_add(v2f a, v2f b) {
    v2f d;
    asm("v_pk_add_f32 %0, %1, %2" : "=v"(d) : "v"(a), "v"(b));
    return d;
}
__device__ __forceinline__ v2f pk_mul(v2f a, v2f b) {
    v2f d;
    asm("v_pk_mul_f32 %0, %1, %2" : "=v"(d) : "v"(a), "v"(b));
    return d;
}

__device__ __forceinline__ float block_sum(float v, int t, float* tmp8) {
#pragma unroll
    for (int o = 32; o > 0; o >>= 1) v += __shfl_down(v, o, 64);
    __syncthreads();                       // protect tmp8 reuse across calls
    if ((t & 63) == 0) tmp8[t >> 6] = v;
    __syncthreads();
    float s = 0.0f;
#pragma unroll
    for (int w = 0; w < TPB / 64; w++) s += tmp8[w];
    return s;
}

// passA (fused with prev round's combB):
//   prologue: cur_k = max(cur_{k-1}*(1-RS_{k-1}),0); out += sum cur_{k-1}*RR_{k-1};
//             zero RS/RR[k&1] for this round's passB; write cur_k (mc==0 blocks).
//   main:     S[m] += sum_n e, T[m] += sum_n e*cur_k[n]   (atomic partials)
// Rows staged pair-interleaved for packed-fp32 math: s_pa=(x0,x1,y0,y1),
// s_pb=(z0,z1,c1*|p0|^2, c1*|p1|^2), s_cu2=(cu0,cu1).
__global__ __launch_bounds__(TPB, 4) void passA(
    const float* __restrict__ preds, const float* __restrict__ labels,
    const float* __restrict__ curprev, float* __restrict__ curout,
    const float* __restrict__ RSprev, const float* __restrict__ RRprev,
    float* __restrict__ RSz, float* __restrict__ RRz,
    float* __restrict__ Sacc, float* __restrict__ Tacc,
    float* __restrict__ out, float c1, int k)
{
    __shared__ v4f s_pa[TILE / 2];
    __shared__ v4f s_pb[TILE / 2];
    __shared__ v2f s_cu2[TILE / 2];
    __shared__ float s_red[2];
    int blk = blockIdx.x;
    int split = blk & 15, mc = (blk >> 4) & 1, b = blk >> 5;
    int t = threadIdx.x;
    int base = b * NN;

    if (t < TILE) {
        int idx = base + split * TILE + t;
        const float* p = preds + (size_t)idx * 3;
        float px = p[0], py = p[1], pz = p[2];
        float pn = px * px + py * py + pz * pz;
        float cu, contrib = 0.0f;
        if (k == 0) cu = 1.0f;
        else {
            float cup = curprev[idx], rs = RSprev[idx], rr = RRprev[idx];
            contrib = cup * rr;                       // round k-1 result term
            cu = fmaxf(cup * (1.0f - rs), 0.0f);
        }
        int h = t >> 1, par = t & 1;
        float* pa = (float*)&s_pa[h];
        float* pb = (float*)&s_pb[h];
        pa[par] = px; pa[2 + par] = py;
        pb[par] = pz; pb[2 + par] = c1 * pn;
        ((float*)s_cu2)[t] = cu;
        if (mc == 0) {
            curout[idx] = cu;
            RSz[idx] = 0.0f; RRz[idx] = 0.0f;         // for this round's passB
        }
        if (k > 0 && mc == 0) {                        // waves 0,1 fully inside t<128
#pragma unroll
            for (int o = 32; o > 0; o >>= 1) contrib += __shfl_down(contrib, o, 64);
            if ((t & 63) == 0) s_red[t >> 6] = contrib;
        }
    }

    // thread-held columns (labels), prescaled by c1; coefficients as packed pairs
    int m0 = mc * CHUNK + t;
    v2f gx2[CPT], gy2[CPT], gz2[CPT], am2[CPT], Sa2[CPT], Ta2[CPT];
    float n2c1 = -2.0f * c1;
#pragma unroll
    for (int c = 0; c < CPT; c++) {
        int m = m0 + c * TPB;
        const float* l = labels + (size_t)(base + m) * 3;
        float lx = l[0], ly = l[1], lz = l[2];
        float gx = n2c1 * lx, gy = n2c1 * ly, gz = n2c1 * lz;
        float am = c1 * (lx * lx + ly * ly + lz * lz);
        gx2[c] = (v2f){gx, gx}; gy2[c] = (v2f){gy, gy}; gz2[c] = (v2f){gz, gz};
        am2[c] = (v2f){am, am};
        Sa2[c] = (v2f){0.0f, 0.0f}; Ta2[c] = (v2f){0.0f, 0.0f};
    }
    __syncthreads();
    if (k > 0 && mc == 0 && t == 0) atomicAdd(out, s_red[0] + s_red[1]);

#pragma unroll 4
    for (int h = 0; h < TILE / 2; h++) {
        v4f A1 = s_pa[h];          // (x0,x1,y0,y1)
        v4f A2 = s_pb[h];          // (z0,z1,w0,w1)
        v2f cu2 = s_cu2[h];
#pragma unroll
        for (int c = 0; c < CPT; c++) {
            v2f seed = pk_add(A2.zw, am2[c]);
            v2f arg = pk_fma(A1.xy, gx2[c],
                      pk_fma(A1.zw, gy2[c],
                      pk_fma(A2.xy, gz2[c], seed)));
            v2f e2;
            e2.x = fast_exp2(arg.x);
            e2.y = fast_exp2(arg.y);
            Sa2[c] = pk_add(Sa2[c], e2);
            Ta2[c] = pk_fma(e2, cu2, Ta2[c]);
        }
    }
#pragma unroll
    for (int c = 0; c < CPT; c++) {
        int idx = base + m0 + c * TPB;
        atomicAdd(&Sacc[idx], Sa2[c].x + Sa2[c].y);
        atomicAdd(&Tacc[idx], Ta2[c].x + Ta2[c].y);
    }
}

// passB (fused with combA):
//   prologue: per staged column m: cc = cost*bw/D1 (from S,T,cost); nc==0 blocks
//             write cost_{k+1}, zero S/T[(k+1)&1] for next round's passA.
//   main:     RS[n] += sum_m e*cc; RR[n] += sum_m e*cc*pw (via (sum w*arg)/c1).
__global__ __launch_bounds__(TPB, 4) void passB(
    const float* __restrict__ preds, const float* __restrict__ labels,
    const float* __restrict__ Sread, const float* __restrict__ Tread,
    const float* __restrict__ costprev, float* __restrict__ costout,
    float* __restrict__ Sz, float* __restrict__ Tz,
    float* __restrict__ RSacc, float* __restrict__ RRacc,
    float c1, float invc1, int k)
{
    __shared__ v4f s_la[TILE / 2];     // (-2c1*lx pair, -2c1*ly pair)
    __shared__ v4f s_lb[TILE / 2];     // (-2c1*lz pair, c1*|l|^2 pair)
    __shared__ v2f s_cc2[TILE / 2];
    int blk = blockIdx.x;
    int split = blk & 15, nc = (blk >> 4) & 1, b = blk >> 5;
    int t = threadIdx.x;
    int base = b * NN;

    if (t < TILE) {
        int idx = base + split * TILE + t;
        const float* l = labels + (size_t)idx * 3;
        float lx = l[0], ly = l[1], lz = l[2];
        float lm2 = lx * lx + ly * ly + lz * lz;
        float S = Sread[idx], T = Tread[idx];
        float cost = (k == 0) ? 1.0f : costprev[idx];
        float D1 = fmaf(cost, S, EPSF);
        float S2 = cost * T / D1;
        float bw = fminf(cost / (S2 + EPSF), 1.0f);
        float cc = cost * bw / D1;
        int h = t >> 1, par = t & 1;
        float* la = (float*)&s_la[h];
        float* lb = (float*)&s_lb[h];
        float n2c1 = -2.0f * c1;
        la[par] = n2c1 * lx; la[2 + par] = n2c1 * ly;
        lb[par] = n2c1 * lz; lb[2 + par] = c1 * lm2;
        ((float*)s_cc2)[t] = cc;
        if (nc == 0) {
            costout[idx] = fmaxf(fmaf(-S2, bw, cost), 0.0f);
            Sz[idx] = 0.0f; Tz[idx] = 0.0f;            // for next round's passA
        }
    }

    int n0 = nc * CHUNK + t;
    v2f px2[CPT], py2[CPT], pz2[CPT], qq2[CPT], RSa2[CPT], RRa2[CPT];
#pragma unroll
    for (int c = 0; c < CPT; c++) {
        int n = n0 + c * TPB;
        const float* p = preds + (size_t)(base + n) * 3;
        float px = p[0], py = p[1], pz = p[2];
        float qq = c1 * (px * px + py * py + pz * pz);
        px2[c] = (v2f){px, px}; py2[c] = (v2f){py, py}; pz2[c] = (v2f){pz, pz};
        qq2[c] = (v2f){qq, qq};
        RSa2[c] = (v2f){0.0f, 0.0f}; RRa2[c] = (v2f){0.0f, 0.0f};
    }
    __syncthreads();

#pragma unroll 4
    for (int h = 0; h < TILE / 2; h++) {
        v4f L1 = s_la[h];
        v4f L2 = s_lb[h];
        v2f cc2 = s_cc2[h];
#pragma unroll
        for (int c = 0; c < CPT; c++) {
            v2f seed = pk_add(L2.zw, qq2[c]);
            v2f arg = pk_fma(L1.xy, px2[c],
                      pk_fma(L1.zw, py2[c],
                      pk_fma(L2.xy, pz2[c], seed)));
            v2f e2;
            e2.x = fast_exp2(arg.x);
            e2.y = fast_exp2(arg.y);
            v2f w2 = pk_mul(e2, cc2);
            RSa2[c] = pk_add(RSa2[c], w2);
            RRa2[c] = pk_fma(w2, arg, RRa2[c]);        // sum w*arg; *1/c1 at end
        }
    }
#pragma unroll
    for (int c = 0; c < CPT; c++) {
        int idx = base + n0 + c * TPB;
        atomicAdd(&RSacc[idx], RSa2[c].x + RSa2[c].y);
        atomicAdd(&RRacc[idx], (RRa2[c].x + RRa2[c].y) * invc1);
    }
}

// Round 9 (ef=0 -> e==1 exactly) collapses algebraically:
//   passA(9): S[m]=2048 (exact const), T[m]=sum_n cur9[n] (batch scalar Cb)
//   passB(9): RR9[n] = sum_m cc*pw = A*|p_n|^2 + B - 2 p_n.V,
//             A=sum cc, B=sum cc*|l|^2, V=sum cc*l   (O(N) reductions)
//   out += sum cur8*RR8 (round-8 term) + sum cur9*RR9 (round-9 term)
__global__ __launch_bounds__(TPB, 1) void k9(
    const float* __restrict__ preds, const float* __restrict__ labels,
    const float* __restrict__ cur8, const float* __restrict__ RS8,
    const float* __restrict__ RR8, const float* __restrict__ cost9,
    float* __restrict__ out)
{
    __shared__ float tmp8[TPB / 64];
    int b = blockIdx.x, t = threadIdx.x;
    int base = b * NN;

    float cu9[K9C];
    float contrib = 0.0f, csum = 0.0f;
#pragma unroll
    for (int c = 0; c < K9C; c++) {
        int idx = base + t + c * TPB;
        float cup = cur8[idx];
        contrib = fmaf(cup, RR8[idx], contrib);       // round-8 result term
        float cu = fmaxf(cup * (1.0f - RS8[idx]), 0.0f);
        cu9[c] = cu; csum += cu;
    }
    float contribT = block_sum(contrib, t, tmp8);
    float Cb = block_sum(csum, t, tmp8);              // T[m] == Cb for all m

    float A = 0.0f, Bs = 0.0f, Vx = 0.0f, Vy = 0.0f, Vz = 0.0f;
#pragma unroll
    for (int c = 0; c < K9C; c++) {
        int idx = base + t + c * TPB;
        const float* l = labels + (size_t)idx * 3;
        float lx = l[0], ly = l[1], lz = l[2];
        float cost = cost9[idx];
        float D1 = fmaf(cost, 2048.0f, EPSF);         // S == 2048 exactly
        float S2 = cost * Cb / D1;
        float bw = fminf(cost / (S2 + EPSF), 1.0f);
        float cc = cost * bw / D1;
        A += cc;
        Bs = fmaf(cc, lx * lx + ly * ly + lz * lz, Bs);
        Vx = fmaf(cc, lx, Vx); Vy = fmaf(cc, ly, Vy); Vz = fmaf(cc, lz, Vz);
    }
    float At  = block_sum(A, t, tmp8);
    float Bt  = block_sum(Bs, t, tmp8);
    float Vxt = block_sum(Vx, t, tmp8);
    float Vyt = block_sum(Vy, t, tmp8);
    float Vzt = block_sum(Vz, t, tmp8);

    float acc = 0.0f;
#pragma unroll
    for (int c = 0; c < K9C; c++) {
        int idx = base + t + c * TPB;
        const float* p = preds + (size_t)idx * 3;
        float x = p[0], y = p[1], z = p[2];
        float pn = x * x + y * y + z * z;
        float rr = fmaf(At, pn, Bt) - 2.0f * (x * Vxt + y * Vyt + z * Vzt);
        acc = fmaf(cu9[c], rr, acc);                  // round-9 result term
    }
    float accT = block_sum(acc, t, tmp8);
    if (t == 0) atomicAdd(out, contribT + accT);
}

extern "C" void kernel_launch(void* const* d_in, const int* in_sizes, int n_in,
                              void* d_out, int out_size, void* d_ws, size_t ws_size,
                              hipStream_t stream) {
    const float* preds  = (const float*)d_in[0];
    const float* labels = (const float*)d_in[1];
    float* out = (float*)d_out;
    float* ws  = (float*)d_ws;

    // layout: S0 T0 S1 T1 RS0 RR0 RS1 RR1 cur0 cur1 cost0 cost1  (12*BN floats = 1.5 MB)
    float* S[2]     = {ws + 0 * BN, ws + 2 * BN};
    float* T[2]     = {ws + 1 * BN, ws + 3 * BN};
    float* RS[2]    = {ws + 4 * BN, ws + 6 * BN};
    float* RR[2]    = {ws + 5 * BN, ws + 7 * BN};
    float* curb[2]  = {ws + 8 * BN, ws + 9 * BN};
    float* costb[2] = {ws + 10 * BN, ws + 11 * BN};

    hipMemsetAsync(d_out, 0, sizeof(float), stream);
    hipMemsetAsync(ws, 0, (size_t)2 * BN * sizeof(float), stream);  // S[0], T[0]

    static const float efs[9] = {-16384.0f, -4096.0f, -1024.0f, -256.0f, -64.0f,
                                 -16.0f, -4.0f, -1.0f, -0.25f};
    const float log2e = 1.44269504088896f;
    for (int k = 0; k < 9; k++) {
        float c1 = efs[k] * log2e;
        float invc1 = 1.0f / c1;
        int pk = k & 1, pp = (k + 1) & 1;   // pp == (k-1)&1 for k>=1
        passA<<<512, TPB, 0, stream>>>(preds, labels,
            curb[pp], curb[pk],     // cur_{k-1} -> cur_k
            RS[pp], RR[pp],         // prev round's row sums
            RS[pk], RR[pk],         // zero for this round's passB
            S[pk], T[pk],           // accumulate this round's col sums
            out, c1, k);
        passB<<<512, TPB, 0, stream>>>(preds, labels,
            S[pk], T[pk],
            costb[pk], costb[pp],   // cost_k -> cost_{k+1}
            S[pp], T[pp],           // zero for next round's passA
            RS[pk], RR[pk],
            c1, invc1, k);
    }
    // after k=8: cur8=curb[0], RS8=RS[0], RR8=RR[0], cost9=costb[1]
    k9<<<BB, TPB, 0, stream>>>(preds, labels, curb[0], RS[0], RR[0], costb[1], out);
}

// Round 7
// 307.959 us; speedup vs baseline: 1.2213x; 1.0057x over previous
//
#include <hip/hip_runtime.h>
#include <cstddef>

#define BB    16
#define NN    2048
#define BN    (BB * NN)
#define EPSF  1e-9f
#define TPB   512
#define CPT   2                 // columns (rows) per thread
#define SPLIT 16                // reduction-dim split
#define TILE  128               // NN/SPLIT rows (or cols) staged per block
#define CHUNK 1024              // TPB*CPT columns (rows) per block
#define K9C   4                 // k9 kernel: 512 threads x 4 = 2048

typedef float v2f __attribute__((ext_vector_type(2)));
typedef float v4f __attribute__((ext_vector_type(4)));

// OCML native exp2 is always linkable; builtin preferred (both -> v_exp_f32).
extern "C" __device__ float __ocml_native_exp2_f32(float);
__device__ __forceinline__ float fast_exp2(float x) {
#if __has_builtin(__builtin_amdgcn_exp2f)
    return __builtin_amdgcn_exp2f(x);
#else
    return __ocml_native_exp2_f32(x);
#endif
}

// Packed fp32 (VOP3P): 2 IEEE fp32 ops per VALU issue slot.
__device__ __forceinline__ v2f pk_fma(v2f a, v2f b, v2f c) {
    v2f d;
    asm("v_pk_fma_f32 %0, %1, %2, %3" : "=v"(d) : "v"(a), "v"(b), "v"(c));
    return d;
}
__device__ __forceinline__ v2f pk_add(v2f a, v2f b) {
    v2f d;
    asm("v_pk_add_f32 %0, %1, %2" : "=v"(d) : "v"(a), "v"(b));
    return d;
}
__device__ __forceinline__ v2f pk_mul(v2f a, v2f b) {
    v2f d;
    asm("v_pk_mul_f32 %0, %1, %2" : "=v"(d) : "v"(a), "v"(b));
    return d;
}

__device__ __forceinline__ float block_sum(float v, int t, float* tmp8) {
#pragma unroll
    for (int o = 32; o > 0; o >>= 1) v += __shfl_down(v, o, 64);
    __syncthreads();                       // protect tmp8 reuse across calls
    if ((t & 63) == 0) tmp8[t >> 6] = v;
    __syncthreads();
    float s = 0.0f;
#pragma unroll
    for (int w = 0; w < TPB / 64; w++) s += tmp8[w];
    return s;
}

// passA (fused with prev round's combB):
//   prologue: cur_k = max(cur_{k-1}*(1-RS_{k-1}),0); out += sum cur_{k-1}*RR_{k-1};
//             zero RS/RR[k&1] for this round's passB; write cur_k (mc==0 blocks).
//   main:     S[m] += sum_n e, T[m] += sum_n e*cur_k[n]   (atomic partials)
// Rows staged pair-interleaved for packed-fp32 math: s_pa=(x0,x1,y0,y1),
// s_pb=(z0,z1,c1*|p0|^2, c1*|p1|^2), s_cu2=(cu0,cu1).
__global__ __launch_bounds__(TPB, 4) void passA(
    const float* __restrict__ preds, const float* __restrict__ labels,
    const float* __restrict__ curprev, float* __restrict__ curout,
    const float* __restrict__ RSprev, const float* __restrict__ RRprev,
    float* __restrict__ RSz, float* __restrict__ RRz,
    float* __restrict__ Sacc, float* __restrict__ Tacc,
    float* __restrict__ out, float c1, int k)
{
    __shared__ v4f s_pa[TILE / 2];
    __shared__ v4f s_pb[TILE / 2];
    __shared__ v2f s_cu2[TILE / 2];
    __shared__ float s_red[2];
    int blk = blockIdx.x;
    int split = blk & 15, mc = (blk >> 4) & 1, b = blk >> 5;
    int t = threadIdx.x;
    int base = b * NN;

    if (t < TILE) {
        int idx = base + split * TILE + t;
        const float* p = preds + (size_t)idx * 3;
        float px = p[0], py = p[1], pz = p[2];
        float pn = px * px + py * py + pz * pz;
        float cu, contrib = 0.0f;
        if (k == 0) cu = 1.0f;
        else {
            float cup = curprev[idx], rs = RSprev[idx], rr = RRprev[idx];
            contrib = cup * rr;                       // round k-1 result term
            cu = fmaxf(cup * (1.0f - rs), 0.0f);
        }
        int h = t >> 1, par = t & 1;
        float* pa = (float*)&s_pa[h];
        float* pb = (float*)&s_pb[h];
        pa[par] = px; pa[2 + par] = py;
        pb[par] = pz; pb[2 + par] = c1 * pn;
        ((float*)s_cu2)[t] = cu;
        if (mc == 0) {
            curout[idx] = cu;
            RSz[idx] = 0.0f; RRz[idx] = 0.0f;         // for this round's passB
        }
        if (k > 0 && mc == 0) {                        // waves 0,1 fully inside t<128
#pragma unroll
            for (int o = 32; o > 0; o >>= 1) contrib += __shfl_down(contrib, o, 64);
            if ((t & 63) == 0) s_red[t >> 6] = contrib;
        }
    }

    // thread-held columns (labels), prescaled by c1; coefficients as packed pairs
    int m0 = mc * CHUNK + t;
    v2f gx2[CPT], gy2[CPT], gz2[CPT], am2[CPT], Sa2[CPT], Ta2[CPT];
    float n2c1 = -2.0f * c1;
#pragma unroll
    for (int c = 0; c < CPT; c++) {
        int m = m0 + c * TPB;
        const float* l = labels + (size_t)(base + m) * 3;
        float lx = l[0], ly = l[1], lz = l[2];
        float gx = n2c1 * lx, gy = n2c1 * ly, gz = n2c1 * lz;
        float am = c1 * (lx * lx + ly * ly + lz * lz);
        gx2[c] = (v2f){gx, gx}; gy2[c] = (v2f){gy, gy}; gz2[c] = (v2f){gz, gz};
        am2[c] = (v2f){am, am};
        Sa2[c] = (v2f){0.0f, 0.0f}; Ta2[c] = (v2f){0.0f, 0.0f};
    }
    __syncthreads();
    if (k > 0 && mc == 0 && t == 0) atomicAdd(out, s_red[0] + s_red[1]);

#pragma unroll 4
    for (int h = 0; h < TILE / 2; h++) {
        v4f A1 = s_pa[h];          // (x0,x1,y0,y1)
        v4f A2 = s_pb[h];          // (z0,z1,w0,w1)
        v2f cu2 = s_cu2[h];
#pragma unroll
        for (int c = 0; c < CPT; c++) {
            v2f seed = pk_add(A2.zw, am2[c]);
            v2f arg = pk_fma(A1.xy, gx2[c],
                      pk_fma(A1.zw, gy2[c],
                      pk_fma(A2.xy, gz2[c], seed)));
            v2f e2;
            e2.x = fast_exp2(arg.x);
            e2.y = fast_exp2(arg.y);
            Sa2[c] = pk_add(Sa2[c], e2);
            Ta2[c] = pk_fma(e2, cu2, Ta2[c]);
        }
    }
#pragma unroll
    for (int c = 0; c < CPT; c++) {
        int idx = base + m0 + c * TPB;
        atomicAdd(&Sacc[idx], Sa2[c].x + Sa2[c].y);
        atomicAdd(&Tacc[idx], Ta2[c].x + Ta2[c].y);
    }
}

// passB (fused with combA):
//   prologue: per staged column m: cc = cost*bw/D1 (from S,T,cost); nc==0 blocks
//             write cost_{k+1}, zero S/T[(k+1)&1] for next round's passA.
//   main:     RS[n] += sum_m e*cc; RR[n] += sum_m e*cc*pw (via (sum w*arg)/c1).
__global__ __launch_bounds__(TPB, 4) void passB(
    const float* __restrict__ preds, const float* __restrict__ labels,
    const float* __restrict__ Sread, const float* __restrict__ Tread,
    const float* __restrict__ costprev, float* __restrict__ costout,
    float* __restrict__ Sz, float* __restrict__ Tz,
    float* __restrict__ RSacc, float* __restrict__ RRacc,
    float c1, float invc1, int k)
{
    __shared__ v4f s_la[TILE / 2];     // (-2c1*lx pair, -2c1*ly pair)
    __shared__ v4f s_lb[TILE / 2];     // (-2c1*lz pair, c1*|l|^2 pair)
    __shared__ v2f s_cc2[TILE / 2];
    int blk = blockIdx.x;
    int split = blk & 15, nc = (blk >> 4) & 1, b = blk >> 5;
    int t = threadIdx.x;
    int base = b * NN;

    if (t < TILE) {
        int idx = base + split * TILE + t;
        const float* l = labels + (size_t)idx * 3;
        float lx = l[0], ly = l[1], lz = l[2];
        float lm2 = lx * lx + ly * ly + lz * lz;
        float S = Sread[idx], T = Tread[idx];
        float cost = (k == 0) ? 1.0f : costprev[idx];
        float D1 = fmaf(cost, S, EPSF);
        float S2 = cost * T / D1;
        float bw = fminf(cost / (S2 + EPSF), 1.0f);
        float cc = cost * bw / D1;
        int h = t >> 1, par = t & 1;
        float* la = (float*)&s_la[h];
        float* lb = (float*)&s_lb[h];
        float n2c1 = -2.0f * c1;
        la[par] = n2c1 * lx; la[2 + par] = n2c1 * ly;
        lb[par] = n2c1 * lz; lb[2 + par] = c1 * lm2;
        ((float*)s_cc2)[t] = cc;
        if (nc == 0) {
            costout[idx] = fmaxf(fmaf(-S2, bw, cost), 0.0f);
            Sz[idx] = 0.0f; Tz[idx] = 0.0f;            // for next round's passA
        }
    }

    int n0 = nc * CHUNK + t;
    v2f px2[CPT], py2[CPT], pz2[CPT], qq2[CPT], RSa2[CPT], RRa2[CPT];
#pragma unroll
    for (int c = 0; c < CPT; c++) {
        int n = n0 + c * TPB;
        const float* p = preds + (size_t)(base + n) * 3;
        float px = p[0], py = p[1], pz = p[2];
        float qq = c1 * (px * px + py * py + pz * pz);
        px2[c] = (v2f){px, px}; py2[c] = (v2f){py, py}; pz2[c] = (v2f){pz, pz};
        qq2[c] = (v2f){qq, qq};
        RSa2[c] = (v2f){0.0f, 0.0f}; RRa2[c] = (v2f){0.0f, 0.0f};
    }
    __syncthreads();

#pragma unroll 4
    for (int h = 0; h < TILE / 2; h++) {
        v4f L1 = s_la[h];
        v4f L2 = s_lb[h];
        v2f cc2 = s_cc2[h];
#pragma unroll
        for (int c = 0; c < CPT; c++) {
            v2f seed = pk_add(L2.zw, qq2[c]);
            v2f arg = pk_fma(L1.xy, px2[c],
                      pk_fma(L1.zw, py2[c],
                      pk_fma(L2.xy, pz2[c], seed)));
            v2f e2;
            e2.x = fast_exp2(arg.x);
            e2.y = fast_exp2(arg.y);
            v2f w2 = pk_mul(e2, cc2);
            RSa2[c] = pk_add(RSa2[c], w2);
            RRa2[c] = pk_fma(w2, arg, RRa2[c]);        // sum w*arg; *1/c1 at end
        }
    }
#pragma unroll
    for (int c = 0; c < CPT; c++) {
        int idx = base + n0 + c * TPB;
        atomicAdd(&RSacc[idx], RSa2[c].x + RSa2[c].y);
        atomicAdd(&RRacc[idx], (RRa2[c].x + RRa2[c].y) * invc1);
    }
}

// Round 9 (ef=0 -> e==1 exactly) collapses algebraically:
//   passA(9): S[m]=2048 (exact const), T[m]=sum_n cur9[n] (batch scalar Cb)
//   passB(9): RR9[n] = sum_m cc*pw = A*|p_n|^2 + B - 2 p_n.V,
//             A=sum cc, B=sum cc*|l|^2, V=sum cc*l   (O(N) reductions)
//   out += sum cur8*RR8 (round-8 term) + sum cur9*RR9 (round-9 term)
__global__ __launch_bounds__(TPB, 1) void k9(
    const float* __restrict__ preds, const float* __restrict__ labels,
    const float* __restrict__ cur8, const float* __restrict__ RS8,
    const float* __restrict__ RR8, const float* __restrict__ cost9,
    float* __restrict__ out)
{
    __shared__ float tmp8[TPB / 64];
    int b = blockIdx.x, t = threadIdx.x;
    int base = b * NN;

    float cu9[K9C];
    float contrib = 0.0f, csum = 0.0f;
#pragma unroll
    for (int c = 0; c < K9C; c++) {
        int idx = base + t + c * TPB;
        float cup = cur8[idx];
        contrib = fmaf(cup, RR8[idx], contrib);       // round-8 result term
        float cu = fmaxf(cup * (1.0f - RS8[idx]), 0.0f);
        cu9[c] = cu; csum += cu;
    }
    float contribT = block_sum(contrib, t, tmp8);
    float Cb = block_sum(csum, t, tmp8);              // T[m] == Cb for all m

    float A = 0.0f, Bs = 0.0f, Vx = 0.0f, Vy = 0.0f, Vz = 0.0f;
#pragma unroll
    for (int c = 0; c < K9C; c++) {
        int idx = base + t + c * TPB;
        const float* l = labels + (size_t)idx * 3;
        float lx = l[0], ly = l[1], lz = l[2];
        float cost = cost9[idx];
        float D1 = fmaf(cost, 2048.0f, EPSF);         // S == 2048 exactly
        float S2 = cost * Cb / D1;
        float bw = fminf(cost / (S2 + EPSF), 1.0f);
        float cc = cost * bw / D1;
        A += cc;
        Bs = fmaf(cc, lx * lx + ly * ly + lz * lz, Bs);
        Vx = fmaf(cc, lx, Vx); Vy = fmaf(cc, ly, Vy); Vz = fmaf(cc, lz, Vz);
    }
    float At  = block_sum(A, t, tmp8);
    float Bt  = block_sum(Bs, t, tmp8);
    float Vxt = block_sum(Vx, t, tmp8);
    float Vyt = block_sum(Vy, t, tmp8);
    float Vzt = block_sum(Vz, t, tmp8);

    float acc = 0.0f;
#pragma unroll
    for (int c = 0; c < K9C; c++) {
        int idx = base + t + c * TPB;
        const float* p = preds + (size_t)idx * 3;
        float x = p[0], y = p[1], z = p[2];
        float pn = x * x + y * y + z * z;
        float rr = fmaf(At, pn, Bt) - 2.0f * (x * Vxt + y * Vyt + z * Vzt);
        acc = fmaf(cu9[c], rr, acc);                  // round-9 result term
    }
    float accT = block_sum(acc, t, tmp8);
    if (t == 0) atomicAdd(out, contribT + accT);
}

extern "C" void kernel_launch(void* const* d_in, const int* in_sizes, int n_in,
                              void* d_out, int out_size, void* d_ws, size_t ws_size,
                              hipStream_t stream) {
    const float* preds  = (const float*)d_in[0];
    const float* labels = (const float*)d_in[1];
    float* out = (float*)d_out;
    float* ws  = (float*)d_ws;

    // layout: S0 T0 S1 T1 RS0 RR0 RS1 RR1 cur0 cur1 cost0 cost1  (12*BN floats = 1.5 MB)
    float* S[2]     = {ws + 0 * BN, ws + 2 * BN};
    float* T[2]     = {ws + 1 * BN, ws + 3 * BN};
    float* RS[2]    = {ws + 4 * BN, ws + 6 * BN};
    float* RR[2]    = {ws + 5 * BN, ws + 7 * BN};
    float* curb[2]  = {ws + 8 * BN, ws + 9 * BN};
    float* costb[2] = {ws + 10 * BN, ws + 11 * BN};

    hipMemsetAsync(d_out, 0, sizeof(float), stream);
    hipMemsetAsync(ws, 0, (size_t)2 * BN * sizeof(float), stream);  // S[0], T[0]

    static const float efs[9] = {-16384.0f, -4096.0f, -1024.0f, -256.0f, -64.0f,
                                 -16.0f, -4.0f, -1.0f, -0.25f};
    const float log2e = 1.44269504088896f;
    for (int k = 0; k < 9; k++) {
        float c1 = efs[k] * log2e;
        float invc1 = 1.0f / c1;
        int pk = k & 1, pp = (k + 1) & 1;   // pp == (k-1)&1 for k>=1
        passA<<<512, TPB, 0, stream>>>(preds, labels,
            curb[pp], curb[pk],     // cur_{k-1} -> cur_k
            RS[pp], RR[pp],         // prev round's row sums
            RS[pk], RR[pk],         // zero for this round's passB
            S[pk], T[pk],           // accumulate this round's col sums
            out, c1, k);
        passB<<<512, TPB, 0, stream>>>(preds, labels,
            S[pk], T[pk],
            costb[pk], costb[pp],   // cost_k -> cost_{k+1}
            S[pp], T[pp],           // zero for next round's passA
            RS[pk], RR[pk],
            c1, invc1, k);
    }
    // after k=8: cur8=curb[0], RS8=RS[0], RR8=RR[0], cost9=costb[1]
    k9<<<BB, TPB, 0, stream>>>(preds, labels, curb[0], RS[0], RR[0], costb[1], out);
}